// Round 2
// baseline (4562.775 us; speedup 1.0000x reference)
//
#include <hip/hip_runtime.h>
#include <math.h>

// Problem constants
#define NTOK 131072
#define NEXP 64
#define KDIM 1024
#define NBINS 4096
#define CAP 8192
// 0-based ascending ranks for the column quantile (q=0.75, n=131072):
// idx = 0.75*(131071) = 98303.25 -> s[98303] + 0.25*(s[98304]-s[98303])
#define RLO 98303u
#define RHI 98304u

// GEMM tiling
#define TT 256     // tokens per block
#define BK 16      // k per tile

__device__ __forceinline__ int bin_of(float v) {
    int bn = (int)floorf((v + 8.0f) * 256.0f);   // 4096 bins over [-8, 8)
    bn = bn < 0 ? 0 : bn;
    bn = bn > (NBINS - 1) ? (NBINS - 1) : bn;
    return bn;
}

// async global->LDS, 16B per lane; LDS dest is wave-uniform base + lane*16
__device__ __forceinline__ void gl_lds16(const void* g, void* l) {
    __builtin_amdgcn_global_load_lds((const __attribute__((address_space(1))) void*)g,
                                     (__attribute__((address_space(3))) void*)l,
                                     16, 0, 0);
}

// ---------------- A0: transpose W [64,1024] -> WT [1024,64] ----------------
__global__ void transpose_w_kernel(const float* __restrict__ W, float* __restrict__ Wt) {
    __shared__ float tile[64][65];
    const int bk = blockIdx.x * 64;            // k-range of this tile
    const int j = threadIdx.x & 63, i = threadIdx.x >> 6;   // 256 thr: i=0..3
    #pragma unroll
    for (int r = 0; r < 16; ++r) {             // expert e = 4r+i reads k coalesced
        int e = 4 * r + i;
        tile[e][j] = W[e * 1024 + bk + j];
    }
    __syncthreads();
    #pragma unroll
    for (int r = 0; r < 16; ++r) {             // k-row 4r+i writes e coalesced
        int k = 4 * r + i;
        Wt[(long)(bk + k) * 64 + j] = tile[j][k];
    }
}

// ---------------- A: fp32 GEMM + bias + noise + histogram ----------------
// block: 128 thr (2 waves); tile 256 tokens x 64 experts; BK=16; microtile 16x8
// LDS: double-buffered; x chunks XOR-swizzled; staged via global_load_lds(16B)
__device__ __forceinline__ void stage_tile(const float* __restrict__ x,
                                           const float* __restrict__ Wt,
                                           long tb, int kt, int tid,
                                           float4* xbuf, float4* wbuf) {
    #pragma unroll
    for (int s = 0; s < 8; ++s) {
        int q = s * 128 + tid;                  // float4 slot 0..1023
        int t = s * 32 + (tid >> 2);            // token row in tile
        int c = (tid & 3) ^ ((2 * s + (tid >> 6)) & 3);   // swizzled k-chunk
        const float* g = x + (tb + t) * 1024 + kt + 4 * c;
        gl_lds16(g, (void*)(xbuf + q));
    }
    #pragma unroll
    for (int s = 0; s < 2; ++s) {
        int q = s * 128 + tid;                  // float4 slot 0..255
        const float* g = Wt + (long)kt * 64 + q * 4;
        gl_lds16(g, (void*)(wbuf + q));
    }
}

__device__ __forceinline__ void compute_tile(const float4* __restrict__ xb,
                                             const float4* __restrict__ wb,
                                             float acc[16][8], int tx, int ty) {
    #pragma unroll
    for (int c = 0; c < 4; ++c) {
        const int cp = c ^ (ty & 3);            // un-swizzle
        float4 xv[16];
        #pragma unroll
        for (int j = 0; j < 16; ++j) xv[j] = xb[64 * ty + 4 * j + cp];
        #pragma unroll
        for (int kk = 0; kk < 4; ++kk) {
            float4 w0 = wb[(4 * c + kk) * 16 + 2 * tx];
            float4 w1 = wb[(4 * c + kk) * 16 + 2 * tx + 1];
            #pragma unroll
            for (int j = 0; j < 16; ++j) {
                float xx = (kk == 0) ? xv[j].x : (kk == 1) ? xv[j].y
                         : (kk == 2) ? xv[j].z : xv[j].w;
                acc[j][0] = fmaf(xx, w0.x, acc[j][0]);
                acc[j][1] = fmaf(xx, w0.y, acc[j][1]);
                acc[j][2] = fmaf(xx, w0.z, acc[j][2]);
                acc[j][3] = fmaf(xx, w0.w, acc[j][3]);
                acc[j][4] = fmaf(xx, w1.x, acc[j][4]);
                acc[j][5] = fmaf(xx, w1.y, acc[j][5]);
                acc[j][6] = fmaf(xx, w1.z, acc[j][6]);
                acc[j][7] = fmaf(xx, w1.w, acc[j][7]);
            }
        }
    }
}

__global__ __launch_bounds__(128, 1)
void gemm_kernel(const float* __restrict__ x, const float* __restrict__ noise,
                 const float* __restrict__ Wt, const float* __restrict__ b,
                 float* __restrict__ logits, unsigned int* __restrict__ hist) {
    __shared__ float4 ldsX[2][1024];   // [buf][t*4 + swizzled chunk] : 32 KB
    __shared__ float4 ldsW[2][256];    // [buf][k*16 + e/4]           : 8 KB

    const int tid = threadIdx.x;
    const int tx = tid & 7;            // expert group: e0 = 8*tx
    const int ty = tid >> 3;           // token group: t0 = 16*ty
    const long tb = (long)blockIdx.x * TT;

    float acc[16][8];
    #pragma unroll
    for (int j = 0; j < 16; ++j)
        #pragma unroll
        for (int e = 0; e < 8; ++e) acc[j][e] = 0.0f;

    stage_tile(x, Wt, tb, 0, tid, ldsX[0], ldsW[0]);

    #pragma unroll 1
    for (int it = 0; it < KDIM / (2 * BK); ++it) {
        int kt = it * 2 * BK;
        __syncthreads();
        if (kt + BK < KDIM) stage_tile(x, Wt, tb, kt + BK, tid, ldsX[1], ldsW[1]);
        compute_tile(ldsX[0], ldsW[0], acc, tx, ty);
        __syncthreads();
        if (kt + 2 * BK < KDIM) stage_tile(x, Wt, tb, kt + 2 * BK, tid, ldsX[0], ldsW[0]);
        compute_tile(ldsX[1], ldsW[1], acc, tx, ty);
    }

    // epilogue: bias + noise, store, histogram
    const float4* b4 = (const float4*)b;
    const float4 bb0 = b4[2 * tx], bb1 = b4[2 * tx + 1];
    const float4* noise4 = (const float4*)noise;
    float4* logits4 = (float4*)logits;
    const int e0 = 8 * tx;
    #pragma unroll 1
    for (int j = 0; j < 16; ++j) {
        long t = tb + 16 * ty + j;
        float4 nz0 = noise4[t * 16 + 2 * tx];
        float4 nz1 = noise4[t * 16 + 2 * tx + 1];
        float4 r0, r1;
        r0.x = acc[j][0] + bb0.x + 0.1f * nz0.x;
        r0.y = acc[j][1] + bb0.y + 0.1f * nz0.y;
        r0.z = acc[j][2] + bb0.z + 0.1f * nz0.z;
        r0.w = acc[j][3] + bb0.w + 0.1f * nz0.w;
        r1.x = acc[j][4] + bb1.x + 0.1f * nz1.x;
        r1.y = acc[j][5] + bb1.y + 0.1f * nz1.y;
        r1.z = acc[j][6] + bb1.z + 0.1f * nz1.z;
        r1.w = acc[j][7] + bb1.w + 0.1f * nz1.w;
        logits4[t * 16 + 2 * tx] = r0;
        logits4[t * 16 + 2 * tx + 1] = r1;
        atomicAdd(&hist[(e0 + 0) * NBINS + bin_of(r0.x)], 1u);
        atomicAdd(&hist[(e0 + 1) * NBINS + bin_of(r0.y)], 1u);
        atomicAdd(&hist[(e0 + 2) * NBINS + bin_of(r0.z)], 1u);
        atomicAdd(&hist[(e0 + 3) * NBINS + bin_of(r0.w)], 1u);
        atomicAdd(&hist[(e0 + 4) * NBINS + bin_of(r1.x)], 1u);
        atomicAdd(&hist[(e0 + 5) * NBINS + bin_of(r1.y)], 1u);
        atomicAdd(&hist[(e0 + 6) * NBINS + bin_of(r1.z)], 1u);
        atomicAdd(&hist[(e0 + 7) * NBINS + bin_of(r1.w)], 1u);
    }
}

// ---------------- B1: find the bins holding ranks RLO/RHI per expert ----------------
__global__ void find_bins_kernel(const unsigned int* __restrict__ hist,
                                 int* __restrict__ blo, int* __restrict__ bhi,
                                 int* __restrict__ basearr) {
    __shared__ unsigned int psum[256];
    const int e = blockIdx.x, tid = threadIdx.x;
    const unsigned int* h = hist + e * NBINS;
    unsigned int loc[16];
    unsigned int s = 0;
    #pragma unroll
    for (int i = 0; i < 16; ++i) { loc[i] = h[tid * 16 + i]; s += loc[i]; }
    psum[tid] = s;
    __syncthreads();
    for (int off = 1; off < 256; off <<= 1) {       // inclusive scan
        unsigned int vv = (tid >= off) ? psum[tid - off] : 0u;
        __syncthreads();
        psum[tid] += vv;
        __syncthreads();
    }
    unsigned int cum = (tid == 0) ? 0u : psum[tid - 1];
    #pragma unroll
    for (int i = 0; i < 16; ++i) {
        unsigned int nb = cum + loc[i];
        if (cum <= RLO && RLO < nb) { blo[e] = tid * 16 + i; basearr[e] = (int)cum; }
        if (cum <= RHI && RHI < nb) { bhi[e] = tid * 16 + i; }
        cum = nb;
    }
}

// ---------------- B2: extract candidate values in bins [blo..bhi] ----------------
__global__ void extract_kernel(const float* __restrict__ logits,
                               const int* __restrict__ blo, const int* __restrict__ bhi,
                               unsigned int* __restrict__ cnt, float* __restrict__ cand) {
    int i = blockIdx.x * 256 + threadIdx.x;     // 8388608 elements
    float v = logits[i];
    int e = i & 63;
    int bn = bin_of(v);
    if (bn >= blo[e] && bn <= bhi[e]) {
        unsigned int p = atomicAdd(&cnt[e], 1u);
        if (p < CAP) cand[e * CAP + p] = v;
    }
}

// ---------------- B3: sort candidates, compute exact column cut ----------------
__global__ void cuts_kernel(const float* __restrict__ cand, const unsigned int* __restrict__ cnt,
                            const int* __restrict__ basearr, float* __restrict__ cut) {
    __shared__ float s[CAP];
    const int e = blockIdx.x, tid = threadIdx.x;
    int n = (int)min(cnt[e], (unsigned int)CAP);
    int np2 = 2; while (np2 < n) np2 <<= 1;
    for (int i = tid; i < np2; i += 256) s[i] = (i < n) ? cand[e * CAP + i] : 3.0e38f;
    __syncthreads();
    for (int k = 2; k <= np2; k <<= 1) {
        for (int j = k >> 1; j > 0; j >>= 1) {
            for (int i = tid; i < np2; i += 256) {
                int ixj = i ^ j;
                if (ixj > i) {
                    float a = s[i], bb = s[ixj];
                    bool up = ((i & k) == 0);
                    if (up ? (a > bb) : (a < bb)) { s[i] = bb; s[ixj] = a; }
                }
            }
            __syncthreads();
        }
    }
    if (tid == 0) {
        int base = basearr[e];
        int r1 = (int)RLO - base, r2 = (int)RHI - base;
        r1 = max(0, min(r1, np2 - 1));
        r2 = max(0, min(r2, np2 - 1));
        float s1 = s[r1], s2 = s[r2];
        cut[e] = s1 + 0.25f * (s2 - s1);
    }
}

// ---------------- C: per-row top-2 mask + softmax (wave per row) ----------------
__device__ __forceinline__ float wave_max_f(float v) {
    #pragma unroll
    for (int off = 32; off > 0; off >>= 1) v = fmaxf(v, __shfl_xor(v, off));
    return v;
}
__device__ __forceinline__ float wave_sum_f(float v) {
    #pragma unroll
    for (int off = 32; off > 0; off >>= 1) v += __shfl_xor(v, off);
    return v;
}
__device__ __forceinline__ double wave_max_d(double v) {
    #pragma unroll
    for (int off = 32; off > 0; off >>= 1) { double o = __shfl_xor(v, off); v = (o > v) ? o : v; }
    return v;
}
__device__ __forceinline__ double wave_sum_d(double v) {
    #pragma unroll
    for (int off = 32; off > 0; off >>= 1) v += __shfl_xor(v, off);
    return v;
}

__global__ __launch_bounds__(256)
void finalize_kernel(const float* __restrict__ logits, const float* __restrict__ cut,
                     const float* __restrict__ x, const float* __restrict__ W,
                     const float* __restrict__ noise, const float* __restrict__ b,
                     float* __restrict__ out) {
    const int tid = threadIdx.x;
    const int lane = tid & 63;                       // lane == expert
    const long row = (long)blockIdx.x * 4 + (tid >> 6);
    const float c = cut[lane];
    const float v = logits[row * 64 + lane];
    float m = (v > c) ? v : -100000.0f;

    float v1 = wave_max_f(m);
    unsigned long long b1m = __ballot(m == v1);
    int l1 = __ffsll((unsigned long long)b1m) - 1;
    float mm = (lane == l1) ? -INFINITY : m;
    float v2 = wave_max_f(mm);
    unsigned long long b2m = __ballot(mm == v2);
    int l2 = __ffsll((unsigned long long)b2m) - 1;
    float mmm = (lane == l2) ? -INFINITY : mm;
    float v3 = wave_max_f(mmm);

    // row quantile: q=0.96875, n=64 -> s[61] + 0.03125*(s[62]-s[61])
    float qr = v3 + 0.03125f * (v2 - v3);
    bool kept = m > qr;
    int cntk = __popcll(__ballot(kept));
    bool risky = (cntk != 2) || (v2 - v3 < 1e-4f);   // wave-uniform

    if (!risky) {
        float ex = kept ? expf(m - v1) : 0.0f;
        float Z = wave_sum_f(ex);
        out[row * 64 + lane] = ex / Z;
        return;
    }
    // fp64 repair: recompute this row's logits exactly; rare
    const float* xr = x + row * 1024;
    const float* wr = W + (long)lane * 1024;
    double a0 = 0.0, a1 = 0.0, a2 = 0.0, a3 = 0.0;
    for (int k = 0; k < 1024; k += 4) {
        a0 += (double)xr[k + 0] * (double)wr[k + 0];
        a1 += (double)xr[k + 1] * (double)wr[k + 1];
        a2 += (double)xr[k + 2] * (double)wr[k + 2];
        a3 += (double)xr[k + 3] * (double)wr[k + 3];
    }
    double lg = ((a0 + a1) + (a2 + a3)) + (double)b[lane] + 0.1 * (double)noise[row * 64 + lane];
    double md = (lg > (double)c) ? lg : -100000.0;
    double d1 = wave_max_d(md);
    unsigned long long db1 = __ballot(md == d1);
    int dl1 = __ffsll((unsigned long long)db1) - 1;
    double md2 = (lane == dl1) ? -(double)INFINITY : md;
    double d2 = wave_max_d(md2);
    unsigned long long db2 = __ballot(md2 == d2);
    int dl2 = __ffsll((unsigned long long)db2) - 1;
    double md3 = (lane == dl2) ? -(double)INFINITY : md2;
    double d3 = wave_max_d(md3);
    double qrd = d3 + 0.03125 * (d2 - d3);
    bool kd = md > qrd;
    int cd = __popcll(__ballot(kd));
    double od;
    if (cd == 0) od = 1.0 / 64.0;
    else {
        double exd = kd ? exp(md - d1) : 0.0;
        double Zd = wave_sum_d(exd);
        od = exd / Zd;
    }
    out[row * 64 + lane] = (float)od;
}

// ---------------- host ----------------
extern "C" void kernel_launch(void* const* d_in, const int* in_sizes, int n_in,
                              void* d_out, int out_size, void* d_ws, size_t ws_size,
                              hipStream_t stream) {
    const float* x     = (const float*)d_in[0];   // [131072,1024]
    const float* noise = (const float*)d_in[1];   // [131072,64]
    const float* W     = (const float*)d_in[2];   // [64,1024]
    const float* b     = (const float*)d_in[3];   // [64]
    float* out = (float*)d_out;                   // [131072,64]; doubles as logits scratch

    char* ws = (char*)d_ws;
    float*        Wt      = (float*)(ws + 0);             // 262144 B
    unsigned int* hist    = (unsigned int*)(ws + 262144); // 1048576 B
    unsigned int* cnt     = (unsigned int*)(ws + 1310720);// 256 B
    int*          blo     = (int*)(ws + 1310976);
    int*          bhi     = (int*)(ws + 1311232);
    int*          basearr = (int*)(ws + 1311488);
    float*        cut     = (float*)(ws + 1311744);
    float*        cand    = (float*)(ws + 1312000);       // 2097152 B; total ~3.3 MB

    hipMemsetAsync(hist, 0, 1048576 + 256, stream);       // hist + cnt contiguous

    hipLaunchKernelGGL(transpose_w_kernel, dim3(16), dim3(256), 0, stream, W, Wt);
    hipLaunchKernelGGL(gemm_kernel, dim3(NTOK / TT), dim3(128), 0, stream,
                       x, noise, Wt, b, out, hist);
    hipLaunchKernelGGL(find_bins_kernel, dim3(64), dim3(256), 0, stream,
                       hist, blo, bhi, basearr);
    hipLaunchKernelGGL(extract_kernel, dim3((NTOK * NEXP) / 256), dim3(256), 0, stream,
                       out, blo, bhi, cnt, cand);
    hipLaunchKernelGGL(cuts_kernel, dim3(64), dim3(256), 0, stream,
                       cand, cnt, basearr, cut);
    hipLaunchKernelGGL(finalize_kernel, dim3(NTOK / 4), dim3(256), 0, stream,
                       out, cut, x, W, noise, b, out);
}